// Round 5
// baseline (128.753 us; speedup 1.0000x reference)
//
#include <hip/hip_runtime.h>
#include <hip/hip_fp16.h>
#include <stdint.h>

#define IN_F 8192
#define OUT_F 8192
#define NGROUPS 64
#define QW_COLS 1024   // IN_F/8 packed int32 per output row
#define QZ_COLS 8
#define M_TOTAL 128
#define BN 128
#define KSPLIT 8
#define KRANGE (IN_F / KSPLIT)  // 1024
#define BK 64
#define NITER (KRANGE / BK)     // 16
#define NTILES (OUT_F / BN)     // 64
#define K16S (IN_F / 16)        // 512

typedef _Float16 half8 __attribute__((ext_vector_type(8)));
typedef float floatx16 __attribute__((ext_vector_type(16)));

// Dequant one packed word (8 nibbles) -> 8 f16 in k-order, bit-identical to ref.
__device__ inline uint4 dq_word(uint32_t w, uint32_t hz2u, uint32_t s2u) {
  const __half2 hz2 = __builtin_bit_cast(__half2, hz2u);
  const __half2 s2 = __builtin_bit_cast(__half2, s2u);
  uint32_t r[4];
#pragma unroll
  for (int p = 0; p < 4; ++p) {
    uint32_t t = ((w >> (4 * p)) & 0x000F000Fu) | 0x64006400u;
    __half2 v = __hmul2(__hsub2(__builtin_bit_cast(__half2, t), hz2), s2);
    r[p] = __builtin_bit_cast(uint32_t, v);  // (elem p, elem p+4)
  }
  uint4 o;
  o.x = (r[0] & 0xFFFFu) | (r[1] << 16);
  o.y = (r[2] & 0xFFFFu) | (r[3] << 16);
  o.z = (r[0] >> 16) | (r[1] & 0xFFFF0000u);
  o.w = (r[2] >> 16) | (r[3] & 0xFFFF0000u);
  return o;
}

// Barrier-free register-pipeline GEMM: no LDS at all.
//  - A fragments loaded per-lane directly from fragment-major aT (L2-resident).
//  - B fragments dequanted in-register: one qweight word == one lane fragment
//    (word = qweight[col*1024 + kslice*128 + it*8 + ks*2 + hf], col=n0+nblk*32+l31,
//     hf=lane>>5; dq_word emits 8 halves in k-order == the MFMA B half8).
//  - double-buffered A-frags + q-words, full unroll => all reg indices static.
// EPI 0: fp16 partials part16[bx][oct][tid][8] (coalesced b128 stores).
// EPI 1: atomicAdd into bias-pre-initialized out.
template <int EPI>
__global__ __launch_bounds__(256, 2) void awq_reg(
    const uint16_t* __restrict__ aT, const int* __restrict__ qweight,
    const float* __restrict__ scales, const int* __restrict__ qzeros,
    uint16_t* __restrict__ part16, float* __restrict__ out) {
  const int tid = threadIdx.x;
  const int bx = blockIdx.x;
  const int ntile = bx & (NTILES - 1);
  const int kslice = bx >> 6;          // 0..7
  const int n0 = ntile * BN;

  const int lane = tid & 63;
  const int wave = tid >> 6;           // 0..3
  const int mw = wave >> 1;            // 2 m-waves x 2 n-waves; wave tile 64x64
  const int nw = wave & 1;
  const int l31 = lane & 31;
  const int half = lane >> 5;          // hf: k-half of each 16-k MFMA step

  floatx16 acc[2][2] = {};

  // per-lane B columns for this wave's two nblks
  const long long colA = n0 + (2 * nw) * 32 + l31;
  const long long colB = colA + 32;
  const int* qbA = qweight + colA * QW_COLS + kslice * 128 + half;
  const int* qbB = qweight + colB * QW_COLS + kslice * 128 + half;

  // 8 group scales of this kslice + the one qzeros word, per col
  const float4 sA0 = *(const float4*)(scales + colA * NGROUPS + kslice * 8);
  const float4 sA1 = *(const float4*)(scales + colA * NGROUPS + kslice * 8 + 4);
  const float4 sB0 = *(const float4*)(scales + colB * NGROUPS + kslice * 8);
  const float4 sB1 = *(const float4*)(scales + colB * NGROUPS + kslice * 8 + 4);
  const float sa[8] = {sA0.x, sA0.y, sA0.z, sA0.w, sA1.x, sA1.y, sA1.z, sA1.w};
  const float sb[8] = {sB0.x, sB0.y, sB0.z, sB0.w, sB1.x, sB1.y, sB1.z, sB1.w};
  const uint32_t zwA = (uint32_t)qzeros[colA * QZ_COLS + kslice];
  const uint32_t zwB = (uint32_t)qzeros[colB * QZ_COLS + kslice];

  // A fragment bases (uint16 elems); step t (k16 index in slice) stride = 512
  const uint16_t* am0 =
      aT + (((long long)(2 * mw) * K16S + kslice * 64) * 64 + lane) * 8;
  const uint16_t* am1 =
      aT + (((long long)(2 * mw + 1) * K16S + kslice * 64) * 64 + lane) * 8;

  // double-buffered register pipeline (all indices static under full unroll)
  half8 a0[2][4], a1[2][4];
  uint32_t qA[2][4], qB[2][4];

#pragma unroll
  for (int ks = 0; ks < 4; ++ks) {
    a0[0][ks] = *(const half8*)(am0 + ks * 512);
    a1[0][ks] = *(const half8*)(am1 + ks * 512);
    qA[0][ks] = (uint32_t)qbA[ks * 2];
    qB[0][ks] = (uint32_t)qbB[ks * 2];
  }

#pragma unroll
  for (int it = 0; it < NITER; ++it) {
    const int cur = it & 1;
    const int nxt = cur ^ 1;
    if (it + 1 < NITER) {
#pragma unroll
      for (int ks = 0; ks < 4; ++ks) {
        a0[nxt][ks] = *(const half8*)(am0 + ((it + 1) * 4 + ks) * 512);
        a1[nxt][ks] = *(const half8*)(am1 + ((it + 1) * 4 + ks) * 512);
        qA[nxt][ks] = (uint32_t)qbA[(it + 1) * 8 + ks * 2];
        qB[nxt][ks] = (uint32_t)qbB[(it + 1) * 8 + ks * 2];
      }
    }

    // group within slice (BK=64, GROUP=128): changes every 2 iters
    const int gl = it >> 1;
    const uint32_t zA = (zwA >> (gl * 4)) & 0xFu;
    const uint32_t zB = (zwB >> (gl * 4)) & 0xFu;
    const uint32_t hzA = 0x64006400u | zA | (zA << 16);
    const uint32_t hzB = 0x64006400u | zB | (zB << 16);
    const uint16_t hA = __builtin_bit_cast(uint16_t, __float2half(sa[gl]));
    const uint16_t hB = __builtin_bit_cast(uint16_t, __float2half(sb[gl]));
    const uint32_t s2A = (uint32_t)hA | ((uint32_t)hA << 16);
    const uint32_t s2B = (uint32_t)hB | ((uint32_t)hB << 16);

#pragma unroll
    for (int ks = 0; ks < 4; ++ks) {
      const half8 b0 = __builtin_bit_cast(half8, dq_word(qA[cur][ks], hzA, s2A));
      const half8 b1 = __builtin_bit_cast(half8, dq_word(qB[cur][ks], hzB, s2B));
      acc[0][0] = __builtin_amdgcn_mfma_f32_32x32x16_f16(a0[cur][ks], b0, acc[0][0], 0, 0, 0);
      acc[0][1] = __builtin_amdgcn_mfma_f32_32x32x16_f16(a0[cur][ks], b1, acc[0][1], 0, 0, 0);
      acc[1][0] = __builtin_amdgcn_mfma_f32_32x32x16_f16(a1[cur][ks], b0, acc[1][0], 0, 0, 0);
      acc[1][1] = __builtin_amdgcn_mfma_f32_32x32x16_f16(a1[cur][ks], b1, acc[1][1], 0, 0, 0);
    }
  }

  // epilogue. C/D 32x32: col=lane&31, row=(reg&3)+8*(reg>>2)+4*(lane>>5)
  if (EPI == 0) {
    // oct = j>>3 of the 64 acc floats; im = oct>>2, in2 = (oct>>1)&1,
    // reg = (oct&1)*8 + jj. Layout: part16[((bx*8 + oct)*256 + tid)*8 + jj]
    const long long pbase = ((long long)bx * 8 * 256 + tid) * 8;
#pragma unroll
    for (int oct = 0; oct < 8; ++oct) {
      const int im = oct >> 2;
      const int in2 = (oct >> 1) & 1;
      const int r0 = (oct & 1) * 8;
      union { uint16_t h[8]; uint4 v; } u;
#pragma unroll
      for (int jj = 0; jj < 8; ++jj)
        u.h[jj] = __builtin_bit_cast(uint16_t, __float2half(acc[im][in2][r0 + jj]));
      *(uint4*)(part16 + pbase + oct * (256 * 8)) = u.v;
    }
  } else {
#pragma unroll
    for (int im = 0; im < 2; ++im)
#pragma unroll
      for (int in2 = 0; in2 < 2; ++in2) {
        const int n = n0 + (2 * nw + in2) * 32 + l31;
#pragma unroll
        for (int reg = 0; reg < 16; ++reg) {
          const int m = (2 * mw + im) * 32 + (reg & 3) + 8 * (reg >> 2) + 4 * half;
          atomicAdd(out + (long long)m * OUT_F + n, acc[im][in2][reg]);
        }
      }
  }
}

// reduce: out = bias + sum over KSPLIT fp16 partials.
// grid = NTILES*8 blocks (nt, oct), 256 threads; coalesced uint4 reads,
// 128B-segment out writes (mirrors the awq_reg epilogue bijection).
__global__ __launch_bounds__(256) void reduce_out(const uint16_t* __restrict__ part16,
                                                  const float* __restrict__ bias,
                                                  float* __restrict__ out) {
  const int t = threadIdx.x;
  const int nt = blockIdx.x >> 3;
  const int o = blockIdx.x & 7;

  float s[8] = {0.f, 0.f, 0.f, 0.f, 0.f, 0.f, 0.f, 0.f};
#pragma unroll
  for (int ks = 0; ks < KSPLIT; ++ks) {
    union { uint4 v; uint16_t h[8]; } u;
    u.v = *(const uint4*)(part16 +
                          ((((long long)ks * NTILES + nt) * 8 + o) * 256 + t) * 8);
#pragma unroll
    for (int jj = 0; jj < 8; ++jj)
      s[jj] += __half2float(__builtin_bit_cast(__half, u.h[jj]));
  }

  const int im = o >> 2;
  const int in2 = (o >> 1) & 1;
  const int r0 = (o & 1) * 8;
  const int wave = t >> 6;
  const int mw = wave >> 1;
  const int nw = wave & 1;
  const int l31 = t & 31;
  const int hf = (t >> 5) & 1;

  const int n = nt * BN + (2 * nw + in2) * 32 + l31;
  const float b = bias[n];
#pragma unroll
  for (int jj = 0; jj < 8; ++jj) {
    const int reg = r0 + jj;
    const int m = (2 * mw + im) * 32 + (reg & 3) + 8 * (reg >> 2) + 4 * hf;
    out[(long long)m * OUT_F + n] = s[jj] + b;
  }
}

// prologue: aT = f16(x) fragment-major:
// aT[mblk][k16][hf*32+l31][j] = x[mblk*32 + l31][k16*16 + hf*8 + j]
__global__ __launch_bounds__(256) void prologue(const float* __restrict__ x,
                                                uint16_t* __restrict__ aT) {
  const int t = blockIdx.x * 256 + threadIdx.x;
  const int idx = t * 8;
  const int row = idx >> 13;
  const int col = idx & (IN_F - 1);

  float4 v0 = *(const float4*)(x + idx);
  float4 v1 = *(const float4*)(x + idx + 4);
  union { uint16_t h[8]; uint4 v; } r;
  r.h[0] = __builtin_bit_cast(uint16_t, __float2half(v0.x));
  r.h[1] = __builtin_bit_cast(uint16_t, __float2half(v0.y));
  r.h[2] = __builtin_bit_cast(uint16_t, __float2half(v0.z));
  r.h[3] = __builtin_bit_cast(uint16_t, __float2half(v0.w));
  r.h[4] = __builtin_bit_cast(uint16_t, __float2half(v1.x));
  r.h[5] = __builtin_bit_cast(uint16_t, __float2half(v1.y));
  r.h[6] = __builtin_bit_cast(uint16_t, __float2half(v1.z));
  r.h[7] = __builtin_bit_cast(uint16_t, __float2half(v1.w));

  const int mblk = row >> 5;
  const int l31r = row & 31;
  const int k16 = col >> 4;
  const int hf = (col >> 3) & 1;
  const long long dst = (((long long)mblk * K16S + k16) * 64 + hf * 32 + l31r) * 8;
  *(uint4*)(aT + dst) = r.v;
}

__global__ __launch_bounds__(256) void init_out(const float* __restrict__ bias,
                                                float* __restrict__ out) {
  int idx = (blockIdx.x * 256 + threadIdx.x) * 4;
  float4 b = *(const float4*)(bias + (idx & (OUT_F - 1)));
  *(float4*)(out + idx) = b;
}

// low fallback (no workspace): f32 x reads, single-buffer LDS, atomics.
// BN=128 geometry, 8 K-slices of 1024, BK=128, 8 iters.
#define FB_NTILES 64
__global__ __launch_bounds__(256) void awq_fallback(
    const float* __restrict__ xf32, const int* __restrict__ qweight,
    const float* __restrict__ scales, const int* __restrict__ qzeros,
    float* __restrict__ out) {
  __shared__ uint16_t bT[4 * 8 * 64 * 8];  // 32 KiB

  const int tid = threadIdx.x;
  const int bx = blockIdx.x;
  const int ntile = bx & (FB_NTILES - 1);
  const int kslice = bx >> 6;  // 0..7
  const int n0 = ntile * 128;
  const int kbase = kslice * 1024;

  const int lane = tid & 63;
  const int wave = tid >> 6;
  const int mw = wave >> 1;
  const int nw = wave & 1;
  const int l31 = lane & 31;
  const int half = lane >> 5;

  floatx16 acc[2][2] = {};

  const int wcol = tid >> 1;
  const int wh = tid & 1;
  const long long qw_base = (long long)(n0 + wcol) * QW_COLS + (kbase >> 3) + wh * 8;
  const long long sc_base = (long long)(n0 + wcol) * NGROUPS;
  const long long qz_base = (long long)(n0 + wcol) * QZ_COLS;
  const int bOff = ((wcol >> 5) * 8 * 64 + (wcol & 31)) * 8;

  const long long arow0 = (long long)(mw * 64 + l31) * IN_F + half * 8;
  const long long arow1 = (long long)(mw * 64 + 32 + l31) * IN_F + half * 8;

  for (int it = 0; it < 8; ++it) {
    const int g = kslice * 8 + it;
    const float sf = scales[sc_base + g];
    const int zw = qzeros[qz_base + (g >> 3)];
    const uint32_t z = (uint32_t)(zw >> ((g & 7) * 4)) & 0xFu;
    const uint32_t hz2u = 0x64006400u | z | (z << 16);
    const uint16_t hs = __builtin_bit_cast(uint16_t, __float2half(sf));
    const uint32_t s2u = (uint32_t)hs | ((uint32_t)hs << 16);
    uint4 q0 = *(const uint4*)(qweight + qw_base + it * 16);
    uint4 q1 = *(const uint4*)(qweight + qw_base + it * 16 + 4);

    if (it > 0) __syncthreads();
    const uint32_t w[8] = {q0.x, q0.y, q0.z, q0.w, q1.x, q1.y, q1.z, q1.w};
#pragma unroll
    for (int i = 0; i < 8; ++i) {
      uint4 v = dq_word(w[i], hz2u, s2u);
      *(uint4*)(&bT[bOff + (((wh * 4 + (i >> 1)) * 64 + (i & 1) * 32) * 8)]) = v;
    }
    __syncthreads();

#pragma unroll
    for (int ks = 0; ks < 8; ++ks) {
      const int ko = kbase + it * 128 + ks * 16;
      float4 f0 = *(const float4*)(xf32 + arow0 + ko);
      float4 f1 = *(const float4*)(xf32 + arow0 + ko + 4);
      half8 a0 = half8{(_Float16)f0.x, (_Float16)f0.y, (_Float16)f0.z, (_Float16)f0.w,
                       (_Float16)f1.x, (_Float16)f1.y, (_Float16)f1.z, (_Float16)f1.w};
      float4 g0 = *(const float4*)(xf32 + arow1 + ko);
      float4 g1 = *(const float4*)(xf32 + arow1 + ko + 4);
      half8 a1 = half8{(_Float16)g0.x, (_Float16)g0.y, (_Float16)g0.z, (_Float16)g0.w,
                       (_Float16)g1.x, (_Float16)g1.y, (_Float16)g1.z, (_Float16)g1.w};
      half8 b0 = *(const half8*)(&bT[((nw * 2) * 8 * 64 + ks * 64 + lane) * 8]);
      half8 b1 = *(const half8*)(&bT[((nw * 2 + 1) * 8 * 64 + ks * 64 + lane) * 8]);
      acc[0][0] = __builtin_amdgcn_mfma_f32_32x32x16_f16(a0, b0, acc[0][0], 0, 0, 0);
      acc[0][1] = __builtin_amdgcn_mfma_f32_32x32x16_f16(a0, b1, acc[0][1], 0, 0, 0);
      acc[1][0] = __builtin_amdgcn_mfma_f32_32x32x16_f16(a1, b0, acc[1][0], 0, 0, 0);
      acc[1][1] = __builtin_amdgcn_mfma_f32_32x32x16_f16(a1, b1, acc[1][1], 0, 0, 0);
    }
  }

  const int cn = n0 + nw * 64 + l31;
#pragma unroll
  for (int im = 0; im < 2; ++im)
#pragma unroll
    for (int in2 = 0; in2 < 2; ++in2)
#pragma unroll
      for (int reg = 0; reg < 16; ++reg) {
        int m = mw * 64 + im * 32 + (reg & 3) + 8 * (reg >> 2) + 4 * half;
        atomicAdd(out + (long long)m * OUT_F + cn + in2 * 32, acc[im][in2][reg]);
      }
}

extern "C" void kernel_launch(void* const* d_in, const int* in_sizes, int n_in,
                              void* d_out, int out_size, void* d_ws, size_t ws_size,
                              hipStream_t stream) {
  const float* x = (const float*)d_in[0];
  const int* qw = (const int*)d_in[1];
  const float* sc = (const float*)d_in[2];
  const int* qz = (const int*)d_in[3];
  const float* bias = (const float*)d_in[4];
  float* out = (float*)d_out;

  const size_t aT_bytes = (size_t)M_TOTAL * IN_F * sizeof(uint16_t);               // 2 MiB
  const size_t part_bytes = (size_t)KSPLIT * M_TOTAL * OUT_F * sizeof(uint16_t);   // 16 MiB
  uint16_t* aT = (uint16_t*)d_ws;
  uint16_t* part16 = (uint16_t*)((char*)d_ws + aT_bytes);

  if (ws_size >= aT_bytes + part_bytes) {
    prologue<<<(M_TOTAL * IN_F) / (256 * 8), 256, 0, stream>>>(x, aT);
    awq_reg<0><<<NTILES * KSPLIT, 256, 0, stream>>>(aT, qw, sc, qz, part16, out);
    reduce_out<<<NTILES * 8, 256, 0, stream>>>(part16, bias, out);
  } else if (ws_size >= aT_bytes) {
    init_out<<<(M_TOTAL * OUT_F) / (256 * 4), 256, 0, stream>>>(bias, out);
    prologue<<<(M_TOTAL * IN_F) / (256 * 8), 256, 0, stream>>>(x, aT);
    awq_reg<1><<<NTILES * KSPLIT, 256, 0, stream>>>(aT, qw, sc, qz, nullptr, out);
  } else {
    init_out<<<(M_TOTAL * OUT_F) / (256 * 4), 256, 0, stream>>>(bias, out);
    awq_fallback<<<FB_NTILES * 8, 256, 0, stream>>>(x, qw, sc, qz, out);
  }
}

// Round 6
// 109.251 us; speedup vs baseline: 1.1785x; 1.1785x over previous
//
#include <hip/hip_runtime.h>
#include <hip/hip_fp16.h>
#include <stdint.h>

#define IN_F 8192
#define OUT_F 8192
#define NGROUPS 64
#define QW_COLS 1024   // IN_F/8 packed int32 per output row
#define QZ_COLS 8
#define M_TOTAL 128
#define BN 128
#define KSPLIT 8
#define KRANGE (IN_F / KSPLIT)  // 1024
#define BK 64
#define NITER (KRANGE / BK)     // 16
#define NTILES (OUT_F / BN)     // 64
#define K16S (IN_F / 16)        // 512

typedef _Float16 half8 __attribute__((ext_vector_type(8)));
typedef float floatx16 __attribute__((ext_vector_type(16)));

// Dequant one packed word (8 nibbles) -> 8 f16 in k-order, bit-identical to ref.
__device__ inline uint4 dq_word(uint32_t w, uint32_t hz2u, uint32_t s2u) {
  const __half2 hz2 = __builtin_bit_cast(__half2, hz2u);
  const __half2 s2 = __builtin_bit_cast(__half2, s2u);
  uint32_t r[4];
#pragma unroll
  for (int p = 0; p < 4; ++p) {
    uint32_t t = ((w >> (4 * p)) & 0x000F000Fu) | 0x64006400u;
    __half2 v = __hmul2(__hsub2(__builtin_bit_cast(__half2, t), hz2), s2);
    r[p] = __builtin_bit_cast(uint32_t, v);  // (elem p, elem p+4)
  }
  uint4 o;
  o.x = (r[0] & 0xFFFFu) | (r[1] << 16);
  o.y = (r[2] & 0xFFFFu) | (r[3] << 16);
  o.z = (r[0] >> 16) | (r[1] & 0xFFFF0000u);
  o.w = (r[2] >> 16) | (r[3] & 0xFFFF0000u);
  return o;
}

// dequant this thread's 4 words (k-span 32 of BK=64) into B fragment buffer.
// word i -> ks = wh*2 + (i>>1), hf = i&1 (verified R8 mapping)
__device__ inline void dq4_to_lds(uint4 q, float sf, uint32_t z, uint16_t* bbuf,
                                  int bOff, int wh) {
  const uint32_t hz2u = 0x64006400u | z | (z << 16);
  const uint16_t hs = __builtin_bit_cast(uint16_t, __float2half(sf));
  const uint32_t s2u = (uint32_t)hs | ((uint32_t)hs << 16);
  const uint32_t w[4] = {q.x, q.y, q.z, q.w};
#pragma unroll
  for (int i = 0; i < 4; ++i) {
    uint4 v = dq_word(w[i], hz2u, s2u);
    *(uint4*)(bbuf + bOff + (((wh * 2 + (i >> 1)) * 64 + (i & 1) * 32) * 8)) = v;
  }
}

// Hybrid staging (R6):
//  - B via LDS: thread-per-column coalesced uint4 qweight pipeline ->
//    in-register dequant -> ds_write shuffle (solves the 4KiB/lane B gather
//    that killed the all-register R5 kernel: 64 cache lines per load).
//  - A direct from global: aT is fragment-major & L2-resident, lane-contiguous
//    16B -> register double-buffer, no LDS round trip, no DMA drain at barrier.
// EPI 0: fp16 partials part16[bx][oct][tid][8] (coalesced b128 stores).
// EPI 1: atomicAdd into bias-pre-initialized out.
template <int EPI>
__global__ __launch_bounds__(256, 2) void awq_hyb(
    const uint16_t* __restrict__ aT, const int* __restrict__ qweight,
    const float* __restrict__ scales, const int* __restrict__ qzeros,
    uint16_t* __restrict__ part16, float* __restrict__ out) {
  __shared__ uint16_t bL[2][16 * 512];  // B: 4 nblk x 4 ks = 16 KiB per buf

  const int tid = threadIdx.x;
  const int bx = blockIdx.x;
  const int ntile = bx & (NTILES - 1);
  const int kslice = bx >> 6;          // 0..7
  const int n0 = ntile * BN;

  const int lane = tid & 63;
  const int wave = tid >> 6;           // 0..3
  const int mw = wave >> 1;            // 2 m-waves x 2 n-waves; wave tile 64x64
  const int nw = wave & 1;
  const int l31 = lane & 31;
  const int half = lane >> 5;

  floatx16 acc[2][2] = {};

  // dequant role: col = n0 + (tid>>1); wh = tid&1 selects k-half (32) of BK=64
  const int wcol = tid >> 1;           // 0..127
  const int wh = tid & 1;
  const long long col = n0 + wcol;
  const long long wbase = col * QW_COLS + kslice * 128 + wh * 4;
  const int bOff = (((wcol >> 5) * 4) * 64 + (wcol & 31)) * 8;  // nblk 0..3

  // this kslice covers groups kslice*8 .. +7 == exactly one qzeros word
  const float4 sA = *(const float4*)(scales + col * NGROUPS + kslice * 8);
  const float4 sB = *(const float4*)(scales + col * NGROUPS + kslice * 8 + 4);
  const float sarr[8] = {sA.x, sA.y, sA.z, sA.w, sB.x, sB.y, sB.z, sB.w};
  const uint32_t zword = (uint32_t)qzeros[col * QZ_COLS + kslice];

  // qweight register pipeline, distance 2: q[it] = uint4 at wbase + it*8
  uint4 q0 = *(const uint4*)(qweight + wbase);        // q[0]
  uint4 qs[2];
  qs[1] = *(const uint4*)(qweight + wbase + 8);       // q[1]
  qs[0] = *(const uint4*)(qweight + wbase + 16);      // q[2]

  // A fragment bases (uint16 elems); k16-step stride in slice = 512 elems
  const uint16_t* am0 =
      aT + (((long long)(2 * mw) * K16S + kslice * 64) * 64 + lane) * 8;
  const uint16_t* am1 =
      aT + (((long long)(2 * mw + 1) * K16S + kslice * 64) * 64 + lane) * 8;

  // A register double-buffer (all indices static under full unroll)
  half8 a0[2][4], a1[2][4];
#pragma unroll
  for (int ks = 0; ks < 4; ++ks) {
    a0[0][ks] = *(const half8*)(am0 + ks * 512);
    a1[0][ks] = *(const half8*)(am1 + ks * 512);
  }

  // pre-loop: dequant q[0] into buf 0
  dq4_to_lds(q0, sarr[0], zword & 0xFu, bL[0], bOff, wh);

#pragma unroll
  for (int it = 0; it < NITER; ++it) {
    const int pb = it & 1;
    const int pn = pb ^ 1;
    const int cur = it & 1;
    const int nxt = cur ^ 1;
    __syncthreads();  // drains buf[pb] B ds_writes (lgkm only; no DMA)

    if (it + 1 < NITER) {
      // A register prefetch for it+1 (L2 hits; fly under this iter's MFMA)
#pragma unroll
      for (int ks = 0; ks < 4; ++ks) {
        a0[nxt][ks] = *(const half8*)(am0 + ((it + 1) * 4 + ks) * 512);
        a1[nxt][ks] = *(const half8*)(am1 + ((it + 1) * 4 + ks) * 512);
      }
      // dequant q[it+1] -> buf pn
      const int gl = (it + 1) >> 1;  // group within slice (BK=64, GROUP=128)
      const uint32_t z = (zword >> (gl * 4)) & 0xFu;
      dq4_to_lds(qs[(it + 1) & 1], sarr[gl], z, bL[pn], bOff, wh);
      // refill consumed slot with q[it+3]
      if (it + 3 < NITER)
        qs[(it + 1) & 1] = *(const uint4*)(qweight + wbase + (it + 3) * 8);
    }

    // MFMA phase: A from regs, B from bL[pb]
#pragma unroll
    for (int ks = 0; ks < 4; ++ks) {
      half8 b0 = *(const half8*)(&bL[pb][((2 * nw) * 4 + ks) * 512 + lane * 8]);
      half8 b1 = *(const half8*)(&bL[pb][((2 * nw + 1) * 4 + ks) * 512 + lane * 8]);
      acc[0][0] = __builtin_amdgcn_mfma_f32_32x32x16_f16(a0[cur][ks], b0, acc[0][0], 0, 0, 0);
      acc[0][1] = __builtin_amdgcn_mfma_f32_32x32x16_f16(a0[cur][ks], b1, acc[0][1], 0, 0, 0);
      acc[1][0] = __builtin_amdgcn_mfma_f32_32x32x16_f16(a1[cur][ks], b0, acc[1][0], 0, 0, 0);
      acc[1][1] = __builtin_amdgcn_mfma_f32_32x32x16_f16(a1[cur][ks], b1, acc[1][1], 0, 0, 0);
    }
  }

  // epilogue. C/D 32x32: col=lane&31, row=(reg&3)+8*(reg>>2)+4*(lane>>5)
  if (EPI == 0) {
    // oct = j>>3 of the 64 acc floats; im = oct>>2, in2 = (oct>>1)&1,
    // reg = (oct&1)*8 + jj. Layout: part16[((bx*8 + oct)*256 + tid)*8 + jj]
    const long long pbase = ((long long)bx * 8 * 256 + tid) * 8;
#pragma unroll
    for (int oct = 0; oct < 8; ++oct) {
      const int im = oct >> 2;
      const int in2 = (oct >> 1) & 1;
      const int r0 = (oct & 1) * 8;
      union { uint16_t h[8]; uint4 v; } u;
#pragma unroll
      for (int jj = 0; jj < 8; ++jj)
        u.h[jj] = __builtin_bit_cast(uint16_t, __float2half(acc[im][in2][r0 + jj]));
      *(uint4*)(part16 + pbase + oct * (256 * 8)) = u.v;
    }
  } else {
#pragma unroll
    for (int im = 0; im < 2; ++im)
#pragma unroll
      for (int in2 = 0; in2 < 2; ++in2) {
        const int n = n0 + (2 * nw + in2) * 32 + l31;
#pragma unroll
        for (int reg = 0; reg < 16; ++reg) {
          const int m = (2 * mw + im) * 32 + (reg & 3) + 8 * (reg >> 2) + 4 * half;
          atomicAdd(out + (long long)m * OUT_F + n, acc[im][in2][reg]);
        }
      }
  }
}

// reduce: out = bias + sum over KSPLIT fp16 partials.
// grid = NTILES*8 blocks (nt, oct), 256 threads; coalesced uint4 reads,
// 128B-segment out writes (mirrors the awq_hyb epilogue bijection).
__global__ __launch_bounds__(256) void reduce_out(const uint16_t* __restrict__ part16,
                                                  const float* __restrict__ bias,
                                                  float* __restrict__ out) {
  const int t = threadIdx.x;
  const int nt = blockIdx.x >> 3;
  const int o = blockIdx.x & 7;

  float s[8] = {0.f, 0.f, 0.f, 0.f, 0.f, 0.f, 0.f, 0.f};
#pragma unroll
  for (int ks = 0; ks < KSPLIT; ++ks) {
    union { uint4 v; uint16_t h[8]; } u;
    u.v = *(const uint4*)(part16 +
                          ((((long long)ks * NTILES + nt) * 8 + o) * 256 + t) * 8);
#pragma unroll
    for (int jj = 0; jj < 8; ++jj)
      s[jj] += __half2float(__builtin_bit_cast(__half, u.h[jj]));
  }

  const int im = o >> 2;
  const int in2 = (o >> 1) & 1;
  const int r0 = (o & 1) * 8;
  const int wave = t >> 6;
  const int mw = wave >> 1;
  const int nw = wave & 1;
  const int l31 = t & 31;
  const int hf = (t >> 5) & 1;

  const int n = nt * BN + (2 * nw + in2) * 32 + l31;
  const float b = bias[n];
#pragma unroll
  for (int jj = 0; jj < 8; ++jj) {
    const int reg = r0 + jj;
    const int m = (2 * mw + im) * 32 + (reg & 3) + 8 * (reg >> 2) + 4 * hf;
    out[(long long)m * OUT_F + n] = s[jj] + b;
  }
}

// prologue: aT = f16(x) fragment-major:
// aT[mblk][k16][hf*32+l31][j] = x[mblk*32 + l31][k16*16 + hf*8 + j]
__global__ __launch_bounds__(256) void prologue(const float* __restrict__ x,
                                                uint16_t* __restrict__ aT) {
  const int t = blockIdx.x * 256 + threadIdx.x;
  const int idx = t * 8;
  const int row = idx >> 13;
  const int col = idx & (IN_F - 1);

  float4 v0 = *(const float4*)(x + idx);
  float4 v1 = *(const float4*)(x + idx + 4);
  union { uint16_t h[8]; uint4 v; } r;
  r.h[0] = __builtin_bit_cast(uint16_t, __float2half(v0.x));
  r.h[1] = __builtin_bit_cast(uint16_t, __float2half(v0.y));
  r.h[2] = __builtin_bit_cast(uint16_t, __float2half(v0.z));
  r.h[3] = __builtin_bit_cast(uint16_t, __float2half(v0.w));
  r.h[4] = __builtin_bit_cast(uint16_t, __float2half(v1.x));
  r.h[5] = __builtin_bit_cast(uint16_t, __float2half(v1.y));
  r.h[6] = __builtin_bit_cast(uint16_t, __float2half(v1.z));
  r.h[7] = __builtin_bit_cast(uint16_t, __float2half(v1.w));

  const int mblk = row >> 5;
  const int l31r = row & 31;
  const int k16 = col >> 4;
  const int hf = (col >> 3) & 1;
  const long long dst = (((long long)mblk * K16S + k16) * 64 + hf * 32 + l31r) * 8;
  *(uint4*)(aT + dst) = r.v;
}

__global__ __launch_bounds__(256) void init_out(const float* __restrict__ bias,
                                                float* __restrict__ out) {
  int idx = (blockIdx.x * 256 + threadIdx.x) * 4;
  float4 b = *(const float4*)(bias + (idx & (OUT_F - 1)));
  *(float4*)(out + idx) = b;
}

// low fallback (no workspace): f32 x reads, single-buffer LDS, atomics.
// BN=128 geometry, 8 K-slices of 1024, BK=128, 8 iters.
#define FB_NTILES 64
__global__ __launch_bounds__(256) void awq_fallback(
    const float* __restrict__ xf32, const int* __restrict__ qweight,
    const float* __restrict__ scales, const int* __restrict__ qzeros,
    float* __restrict__ out) {
  __shared__ uint16_t bT[4 * 8 * 64 * 8];  // 32 KiB

  const int tid = threadIdx.x;
  const int bx = blockIdx.x;
  const int ntile = bx & (FB_NTILES - 1);
  const int kslice = bx >> 6;  // 0..7
  const int n0 = ntile * 128;
  const int kbase = kslice * 1024;

  const int lane = tid & 63;
  const int wave = tid >> 6;
  const int mw = wave >> 1;
  const int nw = wave & 1;
  const int l31 = lane & 31;
  const int half = lane >> 5;

  floatx16 acc[2][2] = {};

  const int wcol = tid >> 1;
  const int wh = tid & 1;
  const long long qw_base = (long long)(n0 + wcol) * QW_COLS + (kbase >> 3) + wh * 8;
  const long long sc_base = (long long)(n0 + wcol) * NGROUPS;
  const long long qz_base = (long long)(n0 + wcol) * QZ_COLS;
  const int bOff = ((wcol >> 5) * 8 * 64 + (wcol & 31)) * 8;

  const long long arow0 = (long long)(mw * 64 + l31) * IN_F + half * 8;
  const long long arow1 = (long long)(mw * 64 + 32 + l31) * IN_F + half * 8;

  for (int it = 0; it < 8; ++it) {
    const int g = kslice * 8 + it;
    const float sf = scales[sc_base + g];
    const int zw = qzeros[qz_base + (g >> 3)];
    const uint32_t z = (uint32_t)(zw >> ((g & 7) * 4)) & 0xFu;
    const uint32_t hz2u = 0x64006400u | z | (z << 16);
    const uint16_t hs = __builtin_bit_cast(uint16_t, __float2half(sf));
    const uint32_t s2u = (uint32_t)hs | ((uint32_t)hs << 16);
    uint4 q0 = *(const uint4*)(qweight + qw_base + it * 16);
    uint4 q1 = *(const uint4*)(qweight + qw_base + it * 16 + 4);

    if (it > 0) __syncthreads();
    const uint32_t w[8] = {q0.x, q0.y, q0.z, q0.w, q1.x, q1.y, q1.z, q1.w};
#pragma unroll
    for (int i = 0; i < 8; ++i) {
      uint4 v = dq_word(w[i], hz2u, s2u);
      *(uint4*)(&bT[bOff + (((wh * 4 + (i >> 1)) * 64 + (i & 1) * 32) * 8)]) = v;
    }
    __syncthreads();

#pragma unroll
    for (int ks = 0; ks < 8; ++ks) {
      const int ko = kbase + it * 128 + ks * 16;
      float4 f0 = *(const float4*)(xf32 + arow0 + ko);
      float4 f1 = *(const float4*)(xf32 + arow0 + ko + 4);
      half8 a0 = half8{(_Float16)f0.x, (_Float16)f0.y, (_Float16)f0.z, (_Float16)f0.w,
                       (_Float16)f1.x, (_Float16)f1.y, (_Float16)f1.z, (_Float16)f1.w};
      float4 g0 = *(const float4*)(xf32 + arow1 + ko);
      float4 g1 = *(const float4*)(xf32 + arow1 + ko + 4);
      half8 a1 = half8{(_Float16)g0.x, (_Float16)g0.y, (_Float16)g0.z, (_Float16)g0.w,
                       (_Float16)g1.x, (_Float16)g1.y, (_Float16)g1.z, (_Float16)g1.w};
      half8 b0 = *(const half8*)(&bT[((nw * 2) * 8 * 64 + ks * 64 + lane) * 8]);
      half8 b1 = *(const half8*)(&bT[((nw * 2 + 1) * 8 * 64 + ks * 64 + lane) * 8]);
      acc[0][0] = __builtin_amdgcn_mfma_f32_32x32x16_f16(a0, b0, acc[0][0], 0, 0, 0);
      acc[0][1] = __builtin_amdgcn_mfma_f32_32x32x16_f16(a0, b1, acc[0][1], 0, 0, 0);
      acc[1][0] = __builtin_amdgcn_mfma_f32_32x32x16_f16(a1, b0, acc[1][0], 0, 0, 0);
      acc[1][1] = __builtin_amdgcn_mfma_f32_32x32x16_f16(a1, b1, acc[1][1], 0, 0, 0);
    }
  }

  const int cn = n0 + nw * 64 + l31;
#pragma unroll
  for (int im = 0; im < 2; ++im)
#pragma unroll
    for (int in2 = 0; in2 < 2; ++in2)
#pragma unroll
      for (int reg = 0; reg < 16; ++reg) {
        int m = mw * 64 + im * 32 + (reg & 3) + 8 * (reg >> 2) + 4 * half;
        atomicAdd(out + (long long)m * OUT_F + cn + in2 * 32, acc[im][in2][reg]);
      }
}

extern "C" void kernel_launch(void* const* d_in, const int* in_sizes, int n_in,
                              void* d_out, int out_size, void* d_ws, size_t ws_size,
                              hipStream_t stream) {
  const float* x = (const float*)d_in[0];
  const int* qw = (const int*)d_in[1];
  const float* sc = (const float*)d_in[2];
  const int* qz = (const int*)d_in[3];
  const float* bias = (const float*)d_in[4];
  float* out = (float*)d_out;

  const size_t aT_bytes = (size_t)M_TOTAL * IN_F * sizeof(uint16_t);               // 2 MiB
  const size_t part_bytes = (size_t)KSPLIT * M_TOTAL * OUT_F * sizeof(uint16_t);   // 16 MiB
  uint16_t* aT = (uint16_t*)d_ws;
  uint16_t* part16 = (uint16_t*)((char*)d_ws + aT_bytes);

  if (ws_size >= aT_bytes + part_bytes) {
    prologue<<<(M_TOTAL * IN_F) / (256 * 8), 256, 0, stream>>>(x, aT);
    awq_hyb<0><<<NTILES * KSPLIT, 256, 0, stream>>>(aT, qw, sc, qz, part16, out);
    reduce_out<<<NTILES * 8, 256, 0, stream>>>(part16, bias, out);
  } else if (ws_size >= aT_bytes) {
    init_out<<<(M_TOTAL * OUT_F) / (256 * 4), 256, 0, stream>>>(bias, out);
    prologue<<<(M_TOTAL * IN_F) / (256 * 8), 256, 0, stream>>>(x, aT);
    awq_hyb<1><<<NTILES * KSPLIT, 256, 0, stream>>>(aT, qw, sc, qz, nullptr, out);
  } else {
    init_out<<<(M_TOTAL * OUT_F) / (256 * 4), 256, 0, stream>>>(bias, out);
    awq_fallback<<<FB_NTILES * 8, 256, 0, stream>>>(x, qw, sc, qz, out);
  }
}